// Round 3
// baseline (62.656 us; speedup 1.0000x reference)
//
#include <hip/hip_runtime.h>

#define BB 8
#define CC 20
#define HH 384
#define WW 384
#define NPIX (BB*HH*WW)
#define BIGF 1.0e6f
#define PADSQ 3.0e12f
#define INFF 1.0e30f
#define HALO 12
#define RPB 4              // rows per block in loss kernel
#define TPR 96             // threads per row (4 px each)
#define SROWF 420          // padded row: 12 left + 384 + 24 right
#define SCALE 16777216.0   // 2^24 fixed point

// Kernel 1: vertical EDT for both masks, wave-parallel prefix/suffix min-scan.
// One wave per (b,x) column: lane l owns rows y = 6l..6l+5. Writes d1^2.
// Also zeroes the fixed-point accumulator + completion counter for kernel 2.
__global__ __launch_bounds__(256) void edt_vertical(const int* __restrict__ tgt,
                                                    float* __restrict__ w0,
                                                    float* __restrict__ w1,
                                                    unsigned long long* __restrict__ acc,
                                                    unsigned int* __restrict__ counter) {
    if (blockIdx.x == 0 && threadIdx.x == 0) { *acc = 0ull; *counter = 0u; }

    int lane = threadIdx.x & 63;
    int col = blockIdx.x * 4 + (threadIdx.x >> 6);   // 0..3071
    int b = col / WW, x = col % WW;
    const int* tp = tgt + (size_t)b * HH * WW + x;
    int y0 = lane * 6;

    int tv[6];
    #pragma unroll
    for (int k = 0; k < 6; ++k) tv[k] = tp[(y0 + k) * WW];

    float* outp0 = w0 + (size_t)b * HH * WW + x;
    float* outp1 = w1 + (size_t)b * HH * WW + x;

    #pragma unroll
    for (int m = 0; m < 2; ++m) {
        float p[6];
        float run = INFF;
        #pragma unroll
        for (int k = 0; k < 6; ++k) {
            float c = (tv[k] == m) ? 0.0f : BIGF;
            run = fminf(run, c - (float)(y0 + k));
            p[k] = run;
        }
        float s = run;
        #pragma unroll
        for (int off = 1; off < 64; off <<= 1) {
            float o = __shfl_up(s, off);
            if (lane >= off) s = fminf(s, o);
        }
        float carry = __shfl_up(s, 1);
        if (lane == 0) carry = INFF;

        float q[6];
        run = INFF;
        #pragma unroll
        for (int k = 5; k >= 0; --k) {
            float c = (tv[k] == m) ? 0.0f : BIGF;
            run = fminf(run, c + (float)(y0 + k));
            q[k] = run;
        }
        float sb = run;
        #pragma unroll
        for (int off = 1; off < 64; off <<= 1) {
            float o = __shfl_down(sb, off);
            if (lane < 64 - off) sb = fminf(sb, o);
        }
        float carryb = __shfl_down(sb, 1);
        if (lane == 63) carryb = INFF;

        float* op = (m == 0) ? outp0 : outp1;
        #pragma unroll
        for (int k = 0; k < 6; ++k) {
            float y = (float)(y0 + k);
            float fwd = y + fminf(carry, p[k]);
            float bwd = fminf(carryb, q[k]) - y;
            float d = fminf(fwd, bwd);
            op[(y0 + k) * WW] = d * d;
        }
    }
}

// Kernel 2: fused horizontal min-plus (+-12 window superset), weight, CE,
// deterministic fixed-point reduction, last-block writes mean.
// Block = 384 threads = 4 rows x 96 threads; each thread owns 4 pixels.
__global__ __launch_bounds__(384, 3) void loss_fused(const float* __restrict__ pred,
                                                     const int* __restrict__ tgt,
                                                     const float* __restrict__ w0,
                                                     const float* __restrict__ w1,
                                                     unsigned long long* __restrict__ acc,
                                                     unsigned int* __restrict__ counter,
                                                     float* __restrict__ out) {
    __shared__ float4 sh4[2 * RPB * (SROWF / 4)];
    __shared__ float wred[6];
    float* sh = (float*)sh4;

    int t = threadIdx.x;
    int blk = blockIdx.x;
    int b = blk / (HH / RPB);
    int row0 = (blk % (HH / RPB)) * RPB;

    // cooperative halo load: 2 masks x RPB rows x SROWF floats = 3360
    const int TOT = 2 * RPB * SROWF;
    #pragma unroll
    for (int i = 0; i < 9; ++i) {
        int f = i * 384 + t;
        if (f < TOT) {
            int m = f / (RPB * SROWF);
            int rem = f % (RPB * SROWF);
            int r = rem / SROWF;
            int xo = rem % SROWF - HALO;
            const float* src = m ? w1 : w0;
            float v = PADSQ;
            if (xo >= 0 && xo < WW)
                v = src[((size_t)b * HH + row0 + r) * WW + xo];
            sh[f] = v;
        }
    }

    int r = t / TPR;
    int xg = (t % TPR) * 4;
    int y = row0 + r;

    // target + pred loads (fully coalesced float4/int4)
    const int4 t4 = *(const int4*)(tgt + ((size_t)b * HH + y) * WW + xg);
    float4 pv[CC];
    float4 mx = make_float4(-INFF, -INFF, -INFF, -INFF);
    float4 pt = make_float4(0.f, 0.f, 0.f, 0.f);
    const float* pb = pred + (((size_t)b * CC) * HH + y) * WW + xg;
    #pragma unroll
    for (int c = 0; c < CC; ++c) {
        float4 v = *(const float4*)(pb + (size_t)c * HH * WW);
        pv[c] = v;
        mx.x = fmaxf(mx.x, v.x); mx.y = fmaxf(mx.y, v.y);
        mx.z = fmaxf(mx.z, v.z); mx.w = fmaxf(mx.w, v.w);
        if (c == t4.x) pt.x = v.x;
        if (c == t4.y) pt.y = v.y;
        if (c == t4.z) pt.z = v.z;
        if (c == t4.w) pt.w = v.w;
    }

    __syncthreads();

    // windowed min-plus from LDS via float4 reads
    const float* s0 = sh + r * SROWF;
    const float* s1 = sh + RPB * SROWF + r * SROWF;
    float m0[4] = {PADSQ, PADSQ, PADSQ, PADSQ};
    float m1[4] = {PADSQ, PADSQ, PADSQ, PADSQ};
    #pragma unroll
    for (int i = 0; i < 10; ++i) {
        float4 a = *(const float4*)(s0 + xg + 4 * i);
        float4 bb = *(const float4*)(s1 + xg + 4 * i);
        #define DO_E(compo, eidx)                                            \
        {                                                                    \
            float va = a.compo, vb = bb.compo;                               \
            _Pragma("unroll")                                                \
            for (int p = 0; p < 4; ++p) {                                    \
                int j = 4 * i + (eidx) - HALO - p;                           \
                float dsq = (float)(j * j);                                  \
                m0[p] = fminf(m0[p], va + dsq);                              \
                m1[p] = fminf(m1[p], vb + dsq);                              \
            }                                                                \
        }
        DO_E(x, 0) DO_E(y, 1) DO_E(z, 2) DO_E(w, 3)
        #undef DO_E
    }

    // per-pixel weight + CE
    float val = 0.0f;
    #define DO_P(compo, pidx)                                                \
    {                                                                        \
        float mxp = mx.compo, ptp = pt.compo;                                \
        float S = 0.0f;                                                      \
        _Pragma("unroll")                                                    \
        for (int c = 0; c < CC; ++c) S += __expf(pv[c].compo - mxp);         \
        float ce = mxp + __logf(S) - ptp;                                    \
        float dist = sqrtf(m0[pidx]) + sqrtf(m1[pidx]);                      \
        float wgt = 1.0f + 5.0f * __expf(dist * (-1.0f / 3.0f));             \
        val += ce * wgt;                                                     \
    }
    DO_P(x, 0) DO_P(y, 1) DO_P(z, 2) DO_P(w, 3)
    #undef DO_P

    // deterministic reduction: wave shfl -> LDS -> fixed-point atomic
    #pragma unroll
    for (int off = 32; off; off >>= 1) val += __shfl_down(val, off);
    int wid = t >> 6, lane = t & 63;
    if (lane == 0) wred[wid] = val;
    __syncthreads();
    if (t == 0) {
        float s = 0.0f;
        #pragma unroll
        for (int i = 0; i < 6; ++i) s += wred[i];
        long long q = (long long)((double)s * SCALE);
        atomicAdd(acc, (unsigned long long)q);
        __threadfence();
        unsigned int old = atomicAdd(counter, 1u);
        if (old == (unsigned)(gridDim.x - 1)) {
            unsigned long long tot = atomicAdd(acc, 0ull);
            out[0] = (float)((double)(long long)tot / (SCALE * (double)NPIX));
        }
    }
}

extern "C" void kernel_launch(void* const* d_in, const int* in_sizes, int n_in,
                              void* d_out, int out_size, void* d_ws, size_t ws_size,
                              hipStream_t stream) {
    const float* pred = (const float*)d_in[0];
    const int* tgt = (const int*)d_in[1];
    float* out = (float*)d_out;

    float* w0 = (float*)d_ws;
    float* w1 = w0 + (size_t)NPIX;
    unsigned long long* acc = (unsigned long long*)(w1 + (size_t)NPIX);
    unsigned int* counter = (unsigned int*)(acc + 1);

    edt_vertical<<<(BB * WW) / 4, 256, 0, stream>>>(tgt, w0, w1, acc, counter);
    loss_fused<<<BB * (HH / RPB), 384, 0, stream>>>(pred, tgt, w0, w1, acc, counter, out);
}